// Round 7
// baseline (1997.625 us; speedup 1.0000x reference)
//
#include <hip/hip_runtime.h>
#include <stdint.h>

// Problem dims
#define T_STEPS 512
#define BATCH   64
#define DIN     256
#define HID     512
#define KTOT    768   // DIN + HID
#define NTEAMS  4
#define TB      16
#define KK_X    8     // k-tiles (K=32) covering x part
#define KK_H    16    // k-tiles covering h part
#define KK_ALL  24

// bounded spin: convert any protocol failure into a terminating wrong answer
#define POLL_BOUND (1 << 18)

typedef __bf16 v8bf __attribute__((ext_vector_type(8)));
typedef float  v4f  __attribute__((ext_vector_type(4)));
typedef unsigned int v4u __attribute__((ext_vector_type(4)));

// workspace layout (bytes)
// h slabs now u32 per unit: (bf16 payload << 16) | step_tag  -> tear-proof
#define HBUF_OFF  0                       // [4 team][2 parity][16 brow][512 unit] u32 = 262144
#define WPK_OFF   262144                  // [128 wv][24 kk][64 lane][8] u16 = 3145728
#define XPK_OFF   (WPK_OFF + 3145728)     // [512 t][4 team][8 kk][64 lane][8] u16 = 16777216

// ---- single-instruction asm memory helpers (device scope = sc1 / IC point) ----
#define LOADX4_DEV(d, a, IMM) \
  asm volatile("global_load_dwordx4 %0, %1, off offset:" IMM " sc1" \
               : "=v"(d) : "v"(a) : "memory")
#define ST4_DEV(a, v) \
  asm volatile("global_store_dwordx4 %0, %1, off sc1" :: "v"(a), "v"(v) : "memory")
#define LOADX4(d, a) \
  asm volatile("global_load_dwordx4 %0, %1, off" : "=v"(d) : "v"(a) : "memory")
#define DRAIN_VM() asm volatile("s_waitcnt vmcnt(0)" ::: "memory")

static __device__ __forceinline__ unsigned short f2bf(float x) {
  union { float f; uint32_t u; } v; v.f = x;
  uint32_t r = (v.u + 0x7fffu + ((v.u >> 16) & 1u)) >> 16;
  return (unsigned short)r;
}

static __device__ __forceinline__ float sigm(float x) {
  float e = __builtin_amdgcn_exp2f(-1.44269504f * x);
  return __builtin_amdgcn_rcpf(1.0f + e);
}
static __device__ __forceinline__ float tanh_(float x) {
  float e = __builtin_amdgcn_exp2f(2.88539008f * x);    // exp(2x)
  return 1.0f - 2.0f * __builtin_amdgcn_rcpf(e + 1.0f); // inf-safe -> +/-1
}

// ---- Prologue: pack weights into MFMA A-fragment order (bf16) ---- (R5-proven)
__global__ void pack_w(const float* __restrict__ Wf, const float* __restrict__ Wi,
                       const float* __restrict__ Wg, const float* __restrict__ Wo,
                       unsigned short* __restrict__ wpk) {
  int n = blockIdx.x * 256 + threadIdx.x;           // 128*24*64 = 196608 chunks
  int l  = n & 63;
  int kk = (n >> 6) % KK_ALL;
  int wv = (n >> 6) / KK_ALL;                       // cu*4 + w, 0..127
  int row  = l & 15;
  int gate = row & 3;
  int unit = (wv >> 2) * 16 + (wv & 3) * 4 + (row >> 2);
  int col  = kk * 32 + (l >> 4) * 8;
  const float* W = (gate == 0) ? Wf : (gate == 1) ? Wi : (gate == 2) ? Wg : Wo;
  const float* src = W + (size_t)unit * KTOT + col;
  unsigned short* dst = wpk + (size_t)n * 8;
#pragma unroll
  for (int e = 0; e < 8; e++) dst[e] = f2bf(src[e]);
}

// ---- Prologue: pack x into MFMA B-fragment order (bf16) ---- (R5-proven)
__global__ void pack_x(const float* __restrict__ X, unsigned short* __restrict__ xpk) {
  int n = blockIdx.x * 256 + threadIdx.x;           // 512*4*8*64 = 1048576 chunks
  int l    = n & 63;
  int kk   = (n >> 6) & 7;
  int team = (n >> 9) & 3;
  int t    = n >> 11;
  int b    = team * TB + (l & 15);
  int col  = kk * 32 + (l >> 4) * 8;
  const float* src = X + ((size_t)(t * BATCH + b)) * DIN + col;
  unsigned short* dst = xpk + (size_t)n * 8;
#pragma unroll
  for (int e = 0; e < 8; e++) dst[e] = f2bf(src[e]);
}

// ---- Persistent recurrent kernel ----
// grid 256 x block 256. team = blk&7 (>=NTEAMS exits), cu = blk>>3 (0..31).
// In-band tag protocol: publish is ONE fire-and-forget sc1 store of
// (bf16<<16)|tag words; consumers poll payload+tag in the same load.
// No flags, no publish drain, no barrier-A. One LDS barrier per step.
__global__ void __launch_bounds__(256, 1)
lstm_rec(const float* __restrict__ bf_, const float* __restrict__ bi_,
         const float* __restrict__ bg_, const float* __restrict__ bo_,
         const unsigned short* __restrict__ wpk, const unsigned short* __restrict__ xpk,
         float* __restrict__ out, unsigned int* hbuf) {
  int blk  = blockIdx.x;
  int team = blk & 7;
  if (team >= NTEAMS) return;
  int cu  = blk >> 3;              // 0..31
  int tid = threadIdx.x;
  int w   = tid >> 6, l = tid & 63;
  int brow = l & 15;               // team-local batch row (B-frag col / C col)
  int ul   = l >> 4;               // 0..3
  int u    = cu * 16 + w * 4 + ul; // hidden unit owned by this lane
  int bglob = team * TB + brow;

  __shared__ v4u hls[2048];        // 2 x 16 KB swizzled bf16 h image (double buffer)

  // stationary weight fragments via asm loads (R5-proven; compiler parks in AGPRs)
  v4u wfu[KK_ALL];
  {
    const char* wp = (const char*)(wpk + ((size_t)(cu * 4 + w)) * (KK_ALL * 512) + l * 8);
#pragma unroll
    for (int kk = 0; kk < KK_ALL; kk++) LOADX4(wfu[kk], wp + (size_t)kk * 1024);
    DRAIN_VM();
  }
  float b0 = bf_[u], b1 = bi_[u], b2 = bg_[u], b3 = bo_[u];
  float c = 0.0f, hval = 0.0f;

  // u32 h slabs (parity ring): [brow][unit] u32, row stride 512 u32 = 2048B
  unsigned int* slab0 = hbuf + (size_t)team * 2 * (TB * HID);
  unsigned int* slab1 = slab0 + TB * HID;

  // stage mapping: wave w covers rows w*4..w*4+3; lane covers 128 consecutive
  // bytes (32 units) of its row, as 8 chunks of 16B.
  int srow = w * 4 + (l >> 4);
  int scol = l & 15;

  float* outb = out + (size_t)bglob * HID + u;

  for (int t = 0; t < T_STEPS; t++) {
    // x-part B-frags: plain cached loads (xpk read-only, L2-resident)
    v8bf xf[KK_X];
    {
      const v8bf* xp = (const v8bf*)(xpk + ((size_t)(t * NTEAMS + team)) * (KK_X * 512) + l * 8);
#pragma unroll
      for (int kk = 0; kk < KK_X; kk++) xf[kk] = xp[kk * 64];
    }

    // x-part MFMAs (independent of h)
    v4f acc[4];
    acc[0] = (v4f){b0, b1, b2, b3};
    acc[1] = (v4f){0.f, 0.f, 0.f, 0.f};
    acc[2] = (v4f){0.f, 0.f, 0.f, 0.f};
    acc[3] = (v4f){0.f, 0.f, 0.f, 0.f};
#pragma unroll
    for (int kk = 0; kk < KK_X; kk++)
      acc[kk & 3] = __builtin_amdgcn_mfma_f32_16x16x32_bf16(
          __builtin_bit_cast(v8bf, wfu[kk]), xf[kk], acc[kk & 3], 0, 0, 0);

    // poll+stage this wave's quarter of the h image (tag == t in every word)
    const unsigned int* sb = ((t & 1) ? slab1 : slab0) + (size_t)srow * HID + scol * 32;
    v4u p0, p1, p2, p3, p4, p5, p6, p7;
    if (t > 0) {
      unsigned int tg = (unsigned)t;
      int guard = 0;
      while (true) {
        LOADX4_DEV(p0, sb, "0");   LOADX4_DEV(p1, sb, "16");
        LOADX4_DEV(p2, sb, "32");  LOADX4_DEV(p3, sb, "48");
        LOADX4_DEV(p4, sb, "64");  LOADX4_DEV(p5, sb, "80");
        LOADX4_DEV(p6, sb, "96");  LOADX4_DEV(p7, sb, "112");
        DRAIN_VM();
        __builtin_amdgcn_sched_barrier(0);   // rule #18: check reads asm outputs
        unsigned int m;
        m  = (p0.x ^ tg) | (p0.y ^ tg) | (p0.z ^ tg) | (p0.w ^ tg);
        m |= (p1.x ^ tg) | (p1.y ^ tg) | (p1.z ^ tg) | (p1.w ^ tg);
        m |= (p2.x ^ tg) | (p2.y ^ tg) | (p2.z ^ tg) | (p2.w ^ tg);
        m |= (p3.x ^ tg) | (p3.y ^ tg) | (p3.z ^ tg) | (p3.w ^ tg);
        m |= (p4.x ^ tg) | (p4.y ^ tg) | (p4.z ^ tg) | (p4.w ^ tg);
        m |= (p5.x ^ tg) | (p5.y ^ tg) | (p5.z ^ tg) | (p5.w ^ tg);
        m |= (p6.x ^ tg) | (p6.y ^ tg) | (p6.z ^ tg) | (p6.w ^ tg);
        m |= (p7.x ^ tg) | (p7.y ^ tg) | (p7.z ^ tg) | (p7.w ^ tg);
        m &= 0xFFFFu;
        if (__all(m == 0)) break;
        if (++guard > POLL_BOUND) break;     // degrade, never hang
      }
    } else {
      LOADX4_DEV(p0, sb, "0");   LOADX4_DEV(p1, sb, "16");
      LOADX4_DEV(p2, sb, "32");  LOADX4_DEV(p3, sb, "48");
      LOADX4_DEV(p4, sb, "64");  LOADX4_DEV(p5, sb, "80");
      LOADX4_DEV(p6, sb, "96");  LOADX4_DEV(p7, sb, "112");
      DRAIN_VM();
      __builtin_amdgcn_sched_barrier(0);
    }

    // unpack (bf16 = hi16 of each u32) and write swizzled LDS rows
    char* hl = (char*)hls + (t & 1) * 16384;
    {
      const unsigned int SEL = 0x07060302u;  // out = [S1.b2,S1.b3,S0.b2,S0.b3]
      int ob = (srow * 1024 + scol * 64) ^ ((srow & 7) << 4);
      v4u o;
      o.x = __builtin_amdgcn_perm(p0.y, p0.x, SEL);
      o.y = __builtin_amdgcn_perm(p0.w, p0.z, SEL);
      o.z = __builtin_amdgcn_perm(p1.y, p1.x, SEL);
      o.w = __builtin_amdgcn_perm(p1.w, p1.z, SEL);
      *(v4u*)(hl + (ob ^ 0)) = o;
      o.x = __builtin_amdgcn_perm(p2.y, p2.x, SEL);
      o.y = __builtin_amdgcn_perm(p2.w, p2.z, SEL);
      o.z = __builtin_amdgcn_perm(p3.y, p3.x, SEL);
      o.w = __builtin_amdgcn_perm(p3.w, p3.z, SEL);
      *(v4u*)(hl + (ob ^ 16)) = o;
      o.x = __builtin_amdgcn_perm(p4.y, p4.x, SEL);
      o.y = __builtin_amdgcn_perm(p4.w, p4.z, SEL);
      o.z = __builtin_amdgcn_perm(p5.y, p5.x, SEL);
      o.w = __builtin_amdgcn_perm(p5.w, p5.z, SEL);
      *(v4u*)(hl + (ob ^ 32)) = o;
      o.x = __builtin_amdgcn_perm(p6.y, p6.x, SEL);
      o.y = __builtin_amdgcn_perm(p6.w, p6.z, SEL);
      o.z = __builtin_amdgcn_perm(p7.y, p7.x, SEL);
      o.w = __builtin_amdgcn_perm(p7.w, p7.z, SEL);
      *(v4u*)(hl + (ob ^ 48)) = o;
    }
    __syncthreads();   // one barrier per step (LDS dbuf covers the other hazard)

    // h-part MFMAs from LDS (swizzled reads, R5-proven layout)
#pragma unroll
    for (int kk = 0; kk < KK_H; kk++) {
      int off = (brow * 1024 + kk * 64 + ul * 16) ^ ((brow & 7) << 4);
      v8bf hf = *(const v8bf*)(hl + off);
      acc[kk & 3] = __builtin_amdgcn_mfma_f32_16x16x32_bf16(
          __builtin_bit_cast(v8bf, wfu[KK_X + kk]), hf, acc[kk & 3], 0, 0, 0);
    }
    v4f g4 = (acc[0] + acc[1]) + (acc[2] + acc[3]);

    // gates are lane-local: f,i,g,o for (unit u, batch bglob)
    float fg = sigm(g4[0]);
    float ig = sigm(g4[1]);
    float gg = tanh_(g4[2]);
    float og = sigm(g4[3]);
    c    = fg * c + ig * gg;
    hval = og * tanh_(c);

    if (t < T_STEPS - 1) {
      // publish h_{t+1}: ONE fire-and-forget 16B store per wave (lane<16),
      // each u32 = (bf16 << 16) | tag(t+1). No drain, no barrier, no flag.
      float a0 = __shfl(hval, brow);
      float a1 = __shfl(hval, brow + 16);
      float a2 = __shfl(hval, brow + 32);
      float a3 = __shfl(hval, brow + 48);
      if (l < 16) {
        unsigned int tg = (unsigned)(t + 1);
        v4u pk;
        pk.x = ((unsigned)f2bf(a0) << 16) | tg;
        pk.y = ((unsigned)f2bf(a1) << 16) | tg;
        pk.z = ((unsigned)f2bf(a2) << 16) | tg;
        pk.w = ((unsigned)f2bf(a3) << 16) | tg;
        unsigned int* pd = (((t + 1) & 1) ? slab1 : slab0) + (size_t)brow * HID + cu * 16 + w * 4;
        ST4_DEV(pd, pk);
      }
    }

    // outputs[t][b][u] — plain cached store, off the critical path
    outb[(size_t)t * (BATCH * HID)] = hval;
  }

  // final hx, cx
  float* hx = out + (size_t)T_STEPS * BATCH * HID;
  hx[(size_t)bglob * HID + u] = hval;
  float* cx = hx + BATCH * HID;
  cx[(size_t)bglob * HID + u] = c;
}

extern "C" void kernel_launch(void* const* d_in, const int* in_sizes, int n_in,
                              void* d_out, int out_size, void* d_ws, size_t ws_size,
                              hipStream_t stream) {
  const float* X  = (const float*)d_in[0];
  const float* Wf = (const float*)d_in[1];
  const float* bf = (const float*)d_in[2];
  const float* Wi = (const float*)d_in[3];
  const float* bi = (const float*)d_in[4];
  const float* Wg = (const float*)d_in[5];
  const float* bg = (const float*)d_in[6];
  const float* Wo = (const float*)d_in[7];
  const float* bo = (const float*)d_in[8];
  float* out = (float*)d_out;
  char* ws = (char*)d_ws;

  unsigned int*   hbuf = (unsigned int*)(ws + HBUF_OFF);
  unsigned short* wpk  = (unsigned short*)(ws + WPK_OFF);
  unsigned short* xpk  = (unsigned short*)(ws + XPK_OFF);

  // zero h tag-slabs every call (tags must reset for graph-replay determinism)
  hipMemsetAsync(ws, 0, WPK_OFF, stream);
  pack_w<<<768, 256, 0, stream>>>(Wf, Wi, Wg, Wo, wpk);
  pack_x<<<4096, 256, 0, stream>>>(X, xpk);
  lstm_rec<<<256, 256, 0, stream>>>(bf, bi, bg, bo, wpk, xpk, out, hbuf);
}